// Round 3
// baseline (1465.341 us; speedup 1.0000x reference)
//
#include <hip/hip_runtime.h>
#include <hip/hip_bf16.h>

typedef __attribute__((ext_vector_type(8))) short bf16x8;
typedef __attribute__((ext_vector_type(4))) float f32x4;
typedef unsigned short u16;

#define MFMA16(a, b, c) __builtin_amdgcn_mfma_f32_16x16x32_bf16((a), (b), (c), 0, 0, 0)

__device__ __forceinline__ u16 f2b(float f) {
  union { float f; unsigned u; } x; x.f = f;
  return (u16)((x.u + 0x7FFFu + ((x.u >> 16) & 1u)) >> 16);  // RNE
}

// ---------------- x fp32 -> bf16 ----------------
__global__ __launch_bounds__(256) void k_cvt(const float* __restrict__ in,
                                             u16* __restrict__ out, int n4) {
  int i = blockIdx.x * 256 + threadIdx.x;
  if (i >= n4) return;
  float4 v = ((const float4*)in)[i];
  u16 a = f2b(v.x), b = f2b(v.y), c = f2b(v.z), d = f2b(v.w);
  ((uint2*)out)[i] = make_uint2((unsigned)a | ((unsigned)b << 16),
                                (unsigned)c | ((unsigned)d << 16));
}

// ---------------- transpose+convert: out[C][R] = bf16(in[R][C]) ----------------
__global__ __launch_bounds__(256) void k_packT(const float* __restrict__ in,
                                               u16* __restrict__ out, int R, int C) {
  __shared__ float t[32][33];
  int r0 = blockIdx.x * 32, c0 = blockIdx.y * 32;
  int cx = threadIdx.x & 31, ry = threadIdx.x >> 5;
#pragma unroll
  for (int k = 0; k < 4; k++)
    t[ry + k * 8][cx] = in[(size_t)(r0 + ry + k * 8) * C + c0 + cx];
  __syncthreads();
#pragma unroll
  for (int k = 0; k < 4; k++)
    out[(size_t)(c0 + ry + k * 8) * R + r0 + cx] = f2b(t[cx][ry + k * 8]);
}

// ---------------- q,k projection: [16384][64] each, q pre-scaled by 1/8 ----------------
__global__ __launch_bounds__(256) void k_gemm_qk(const u16* __restrict__ xb,
                                                 const u16* __restrict__ wqt,
                                                 const u16* __restrict__ wkt,
                                                 u16* __restrict__ q, u16* __restrict__ kk) {
  int row0 = blockIdx.x * 64;
  int tid = threadIdx.x, w = tid >> 6, l = tid & 63, l15 = l & 15, lg = l >> 4;
  const u16* wt = (w < 2) ? wqt : wkt;
  int nbase = (w & 1) * 32;
  f32x4 acc[4][2];
#pragma unroll
  for (int mt = 0; mt < 4; mt++)
#pragma unroll
    for (int nt = 0; nt < 2; nt++) acc[mt][nt] = (f32x4){0.f, 0.f, 0.f, 0.f};

  for (int k0 = 0; k0 < 1024; k0 += 32) {
    bf16x8 bfr[2], afr[4];
#pragma unroll
    for (int nt = 0; nt < 2; nt++)
      bfr[nt] = *(const bf16x8*)&wt[(size_t)(nbase + nt * 16 + l15) * 1024 + k0 + lg * 8];
#pragma unroll
    for (int mt = 0; mt < 4; mt++)
      afr[mt] = *(const bf16x8*)&xb[(size_t)(row0 + mt * 16 + l15) * 1024 + k0 + lg * 8];
#pragma unroll
    for (int mt = 0; mt < 4; mt++)
#pragma unroll
      for (int nt = 0; nt < 2; nt++) acc[mt][nt] = MFMA16(afr[mt], bfr[nt], acc[mt][nt]);
  }
  float scale = (w < 2) ? 0.125f : 1.0f;  // fold head_size^-0.5 into q
  u16* dst = (w < 2) ? q : kk;
#pragma unroll
  for (int mt = 0; mt < 4; mt++)
#pragma unroll
    for (int nt = 0; nt < 2; nt++)
#pragma unroll
      for (int j = 0; j < 4; j++)
        dst[(size_t)(row0 + mt * 16 + lg * 4 + j) * 64 + nbase + nt * 16 + l15] =
            f2b(acc[mt][nt][j] * scale);
}

// ---------------- v projection, transposed: vT[b][d][s] ----------------
__global__ __launch_bounds__(256) void k_gemm_v(const u16* __restrict__ xb,
                                                const u16* __restrict__ wvt,
                                                u16* __restrict__ vT) {
  int b = blockIdx.z;
  int m0 = blockIdx.y * 128;  // d_out
  int n0 = blockIdx.x * 128;  // s
  int tid = threadIdx.x, w = tid >> 6, l = tid & 63, l15 = l & 15, lg = l >> 4;
  int nb = n0 + w * 32;
  const u16* xrow = xb + (size_t)(b * 4096 + nb) * 1024;
  f32x4 acc[8][2];
#pragma unroll
  for (int mt = 0; mt < 8; mt++)
#pragma unroll
    for (int nt = 0; nt < 2; nt++) acc[mt][nt] = (f32x4){0.f, 0.f, 0.f, 0.f};

  for (int k0 = 0; k0 < 1024; k0 += 32) {
    bf16x8 bfr[2], afr[8];
#pragma unroll
    for (int nt = 0; nt < 2; nt++)
      bfr[nt] = *(const bf16x8*)&xrow[(size_t)(nt * 16 + l15) * 1024 + k0 + lg * 8];
#pragma unroll
    for (int mt = 0; mt < 8; mt++)
      afr[mt] = *(const bf16x8*)&wvt[(size_t)(m0 + mt * 16 + l15) * 1024 + k0 + lg * 8];
#pragma unroll
    for (int mt = 0; mt < 8; mt++)
#pragma unroll
      for (int nt = 0; nt < 2; nt++) acc[mt][nt] = MFMA16(afr[mt], bfr[nt], acc[mt][nt]);
  }
#pragma unroll
  for (int mt = 0; mt < 8; mt++)
#pragma unroll
    for (int nt = 0; nt < 2; nt++)
#pragma unroll
      for (int j = 0; j < 4; j++)
        vT[((size_t)b * 1024 + m0 + mt * 16 + lg * 4 + j) * 4096 + nb + nt * 16 + l15] =
            f2b(acc[mt][nt][j]);
}

// ---------------- barrier-free, software-pipelined flash attention ----------------
// 8 independent waves/block; wave owns 32 q-rows x 128 d-cols of O^T.
// Pipeline: K(t) prefetched during tile t-1; V(t) issued at top of tile t and
// consumed only after QK+softmax (~1-2k cy of cover). No __syncthreads anywhere.
__global__ __launch_bounds__(512, 2) void k_attn(const u16* __restrict__ qw,
                                                 const u16* __restrict__ kw,
                                                 const u16* __restrict__ vT,
                                                 float* __restrict__ out) {
  int qtile = 15 - blockIdx.x;  // long blocks dispatch first
  int chunk = blockIdx.y, b = blockIdx.z;
  int tid = threadIdx.x, w = tid >> 6, l = tid & 63, l15 = l & 15, lg = l >> 4;
  int qbase = qtile * 256 + w * 32;
  int d0 = chunk * 128;
  size_t tokb = (size_t)b * 4096;

  __shared__ __align__(16) u16 P_all[8 * 2048];  // 4KB per wave, XOR-swizzled
  char* Pb = (char*)&P_all[w * 2048];

  bf16x8 qf[2][2];
#pragma unroll
  for (int qt = 0; qt < 2; qt++)
#pragma unroll
    for (int ks = 0; ks < 2; ks++)
      qf[qt][ks] = *(const bf16x8*)&qw[(tokb + qbase + qt * 16 + l15) * 64 + ks * 32 + lg * 8];

  f32x4 acc[8][2];   // [d-tile][q-subtile]
  f32x4 accl[2];     // running row-sum l via ones-MFMA (PV layout)
  float mrow[2][4];  // running max (QK layout)
#pragma unroll
  for (int mt = 0; mt < 8; mt++)
#pragma unroll
    for (int qt = 0; qt < 2; qt++) acc[mt][qt] = (f32x4){0.f, 0.f, 0.f, 0.f};
#pragma unroll
  for (int qt = 0; qt < 2; qt++) {
    accl[qt] = (f32x4){0.f, 0.f, 0.f, 0.f};
#pragma unroll
    for (int j = 0; j < 4; j++) mrow[qt][j] = -1e30f;
  }
  const short ob = (short)0x3F80;
  const bf16x8 ones = {ob, ob, ob, ob, ob, ob, ob, ob};

  // per-lane base pointers (row part per-lane, tile offsets uniform)
  const u16* kln = kw + (tokb + l15) * 64 + lg * 8;                        // + (s0+nt*16)*64 + ks*32
  const u16* vln = vT + ((size_t)b * 1024 + d0 + l15) * 4096 + lg * 8;     // + mt*16*4096 + s0 (+32)

  int ntiles = ((qbase + 31) >> 6) + 1;

  bf16x8 kcur[4][2], knxt[4][2], vf[8][2];
  // prologue: K(0)
#pragma unroll
  for (int nt = 0; nt < 4; nt++)
#pragma unroll
    for (int ks = 0; ks < 2; ks++)
      kcur[nt][ks] = *(const bf16x8*)&kln[(nt * 16) * 64 + ks * 32];

  for (int t = 0; t < ntiles; t++) {
    int s0 = t * 64;
    // ---- issue V(t): consumed only after QK+softmax ----
#pragma unroll
    for (int mt = 0; mt < 8; mt++) {
      const u16* vr = vln + (size_t)mt * 16 * 4096 + s0;
      vf[mt][0] = *(const bf16x8*)vr;
      vf[mt][1] = *(const bf16x8*)(vr + 32);
    }
    // ---- QK^T from prefetched K ----
    f32x4 sfr[2][4];
#pragma unroll
    for (int nt = 0; nt < 4; nt++)
#pragma unroll
      for (int qt = 0; qt < 2; qt++) {
        f32x4 z = (f32x4){0.f, 0.f, 0.f, 0.f};
        z = MFMA16(qf[qt][0], kcur[nt][0], z);
        sfr[qt][nt] = MFMA16(qf[qt][1], kcur[nt][1], z);
      }
    // ---- issue K(t+1) (clamped; last-tile prefetch is discarded) ----
    int sp = (t + 1 < ntiles ? t + 1 : t) * 64;
#pragma unroll
    for (int nt = 0; nt < 4; nt++)
#pragma unroll
      for (int ks = 0; ks < 2; ks++)
        knxt[nt][ks] = *(const bf16x8*)&kln[(sp + nt * 16) * 64 + ks * 32];

    if (t == ntiles - 1) {  // causal mask on final tile
#pragma unroll
      for (int qt = 0; qt < 2; qt++)
#pragma unroll
        for (int nt = 0; nt < 4; nt++) {
          int sg = s0 + nt * 16 + l15;
#pragma unroll
          for (int j = 0; j < 4; j++)
            if (sg > qbase + qt * 16 + lg * 4 + j) sfr[qt][nt][j] = -1e30f;
        }
    }
    // ---- wave-local row max ----
    float pmax[2][4];
    int need = 0;
#pragma unroll
    for (int qt = 0; qt < 2; qt++) {
#pragma unroll
      for (int j = 0; j < 4; j++)
        pmax[qt][j] = fmaxf(fmaxf(sfr[qt][0][j], sfr[qt][1][j]),
                            fmaxf(sfr[qt][2][j], sfr[qt][3][j]));
#pragma unroll
      for (int msk = 1; msk <= 8; msk <<= 1)
#pragma unroll
        for (int j = 0; j < 4; j++)
          pmax[qt][j] = fmaxf(pmax[qt][j], __shfl_xor(pmax[qt][j], msk));
#pragma unroll
      for (int j = 0; j < 4; j++) need |= (pmax[qt][j] > mrow[qt][j] + 8.0f);
    }
    if (__any(need)) {  // T13 defer-max
      float scq[2];
#pragma unroll
      for (int qt = 0; qt < 2; qt++) {
        float sc[4];
#pragma unroll
        for (int j = 0; j < 4; j++) {
          float mn = fmaxf(mrow[qt][j], pmax[qt][j]);
          sc[j] = __expf(mrow[qt][j] - mn);
          mrow[qt][j] = mn;
        }
        float s = 1.f;
#pragma unroll
        for (int j = 0; j < 4; j++) {  // transpose row-scale -> col-scale
          float tv = __shfl(sc[j], (l15 >> 2) * 16);
          if ((l15 & 3) == j) s = tv;
        }
        scq[qt] = s;
      }
#pragma unroll
      for (int mt = 0; mt < 8; mt++)
#pragma unroll
        for (int qt = 0; qt < 2; qt++) acc[mt][qt] *= scq[qt];
      accl[0] *= scq[0];
      accl[1] *= scq[1];
    }
    // ---- P = exp(S-m) -> wave-private swizzled LDS ----
#pragma unroll
    for (int qt = 0; qt < 2; qt++)
#pragma unroll
      for (int nt = 0; nt < 4; nt++)
#pragma unroll
        for (int j = 0; j < 4; j++) {
          int R = qt * 16 + lg * 4 + j;
          float p = __expf(sfr[qt][nt][j] - mrow[qt][j]);
          int addr = (R * 128 + (nt * 16 + l15) * 2) ^ ((R & 7) << 4);
          *(u16*)(Pb + addr) = f2b(p);
        }
    asm volatile("" ::: "memory");
    bf16x8 pf[2][2];
#pragma unroll
    for (int qt = 0; qt < 2; qt++)
#pragma unroll
      for (int ks = 0; ks < 2; ks++) {
        int R = qt * 16 + l15;
        int addr = (R * 128 + ks * 64 + lg * 16) ^ ((R & 7) << 4);
        pf[qt][ks] = *(const bf16x8*)(Pb + addr);
      }
    // ---- l += colsum(P) ----
#pragma unroll
    for (int qt = 0; qt < 2; qt++) {
      accl[qt] = MFMA16(ones, pf[qt][0], accl[qt]);
      accl[qt] = MFMA16(ones, pf[qt][1], accl[qt]);
    }
    // ---- O^T += V^T P^T (V issued at top of this tile) ----
#pragma unroll
    for (int mt = 0; mt < 8; mt++)
#pragma unroll
      for (int qt = 0; qt < 2; qt++) {
        acc[mt][qt] = MFMA16(vf[mt][0], pf[qt][0], acc[mt][qt]);
        acc[mt][qt] = MFMA16(vf[mt][1], pf[qt][1], acc[mt][qt]);
      }
    // ---- rotate K prefetch ----
#pragma unroll
    for (int nt = 0; nt < 4; nt++)
#pragma unroll
      for (int ks = 0; ks < 2; ks++) kcur[nt][ks] = knxt[nt][ks];
  }
  // ---- epilogue ----
#pragma unroll
  for (int qt = 0; qt < 2; qt++) {
    float linv = 1.0f / accl[qt][0];
#pragma unroll
    for (int mt = 0; mt < 8; mt++) {
      f32x4 v = acc[mt][qt] * linv;
      size_t o = (tokb + qbase + qt * 16 + l15) * 1024 + d0 + mt * 16 + lg * 4;
      *(f32x4*)&out[o] = v;
    }
  }
}

// ---------------- launch ----------------
extern "C" void kernel_launch(void* const* d_in, const int* in_sizes, int n_in,
                              void* d_out, int out_size, void* d_ws, size_t ws_size,
                              hipStream_t stream) {
  const float* x  = (const float*)d_in[0];
  const float* Wq = (const float*)d_in[1];
  const float* Wk = (const float*)d_in[2];
  const float* Wv = (const float*)d_in[3];
  float* out = (float*)d_out;
  char* ws = (char*)d_ws;
  u16* xb  = (u16*)(ws);              // 16384x1024 bf16
  u16* qw  = (u16*)(ws + 33554432);   // 16384x64
  u16* kw  = (u16*)(ws + 35651584);   // 16384x64
  u16* vT  = (u16*)(ws + 37748736);   // 4x1024x4096
  u16* wqt = (u16*)(ws + 71303168);   // 64x1024
  u16* wkt = (u16*)(ws + 71434240);   // 64x1024
  u16* wvt = (u16*)(ws + 71565312);   // 1024x1024

  k_cvt<<<16384, 256, 0, stream>>>(x, xb, 4194304);
  k_packT<<<dim3(32, 2), 256, 0, stream>>>(Wq, wqt, 1024, 64);
  k_packT<<<dim3(32, 2), 256, 0, stream>>>(Wk, wkt, 1024, 64);
  k_packT<<<dim3(32, 32), 256, 0, stream>>>(Wv, wvt, 1024, 1024);
  k_gemm_qk<<<256, 256, 0, stream>>>(xb, wqt, wkt, qw, kw);
  k_gemm_v<<<dim3(32, 8, 4), 256, 0, stream>>>(xb, wvt, vT);
  k_attn<<<dim3(16, 8, 4), 512, 0, stream>>>(qw, kw, vT, out);
}

// Round 4
// 405.589 us; speedup vs baseline: 3.6129x; 3.6129x over previous
//
#include <hip/hip_runtime.h>
#include <hip/hip_bf16.h>

typedef __attribute__((ext_vector_type(8))) short bf16x8;
typedef __attribute__((ext_vector_type(4))) float f32x4;
typedef unsigned short u16;

#define MFMA16(a, b, c) __builtin_amdgcn_mfma_f32_16x16x32_bf16((a), (b), (c), 0, 0, 0)
#define GLLDS(gp, lp)                                                                  \
  __builtin_amdgcn_global_load_lds((const __attribute__((address_space(1))) unsigned int*)(gp), \
                                   (__attribute__((address_space(3))) unsigned int*)(lp), 16, 0, 0)

__device__ __forceinline__ u16 f2b(float f) {
  union { float f; unsigned u; } x; x.f = f;
  return (u16)((x.u + 0x7FFFu + ((x.u >> 16) & 1u)) >> 16);  // RNE
}

// ---------------- x fp32 -> bf16 ----------------
__global__ __launch_bounds__(256) void k_cvt(const float* __restrict__ in,
                                             u16* __restrict__ out, int n4) {
  int i = blockIdx.x * 256 + threadIdx.x;
  if (i >= n4) return;
  float4 v = ((const float4*)in)[i];
  u16 a = f2b(v.x), b = f2b(v.y), c = f2b(v.z), d = f2b(v.w);
  ((uint2*)out)[i] = make_uint2((unsigned)a | ((unsigned)b << 16),
                                (unsigned)c | ((unsigned)d << 16));
}

// ---------------- transpose+convert: out[C][R] = bf16(in[R][C]) ----------------
__global__ __launch_bounds__(256) void k_packT(const float* __restrict__ in,
                                               u16* __restrict__ out, int R, int C) {
  __shared__ float t[32][33];
  int r0 = blockIdx.x * 32, c0 = blockIdx.y * 32;
  int cx = threadIdx.x & 31, ry = threadIdx.x >> 5;
#pragma unroll
  for (int k = 0; k < 4; k++)
    t[ry + k * 8][cx] = in[(size_t)(r0 + ry + k * 8) * C + c0 + cx];
  __syncthreads();
#pragma unroll
  for (int k = 0; k < 4; k++)
    out[(size_t)(c0 + ry + k * 8) * R + r0 + cx] = f2b(t[cx][ry + k * 8]);
}

// ---------------- q,k projection; q linear (pre-scaled 1/8), k swizzle-tile-packed ----------------
// k layout: per 64-token tile: 8KB block, byte addr = (row&63)*128 + ((col*2) ^ ((row&7)<<4))
__global__ __launch_bounds__(256) void k_gemm_qk(const u16* __restrict__ xb,
                                                 const u16* __restrict__ wqt,
                                                 const u16* __restrict__ wkt,
                                                 u16* __restrict__ q, u16* __restrict__ kk) {
  int row0 = blockIdx.x * 64;
  int tid = threadIdx.x, w = tid >> 6, l = tid & 63, l15 = l & 15, lg = l >> 4;
  const u16* wt = (w < 2) ? wqt : wkt;
  int nbase = (w & 1) * 32;
  f32x4 acc[4][2];
#pragma unroll
  for (int mt = 0; mt < 4; mt++)
#pragma unroll
    for (int nt = 0; nt < 2; nt++) acc[mt][nt] = (f32x4){0.f, 0.f, 0.f, 0.f};

  for (int k0 = 0; k0 < 1024; k0 += 32) {
    bf16x8 bfr[2], afr[4];
#pragma unroll
    for (int nt = 0; nt < 2; nt++)
      bfr[nt] = *(const bf16x8*)&wt[(size_t)(nbase + nt * 16 + l15) * 1024 + k0 + lg * 8];
#pragma unroll
    for (int mt = 0; mt < 4; mt++)
      afr[mt] = *(const bf16x8*)&xb[(size_t)(row0 + mt * 16 + l15) * 1024 + k0 + lg * 8];
#pragma unroll
    for (int mt = 0; mt < 4; mt++)
#pragma unroll
      for (int nt = 0; nt < 2; nt++) acc[mt][nt] = MFMA16(afr[mt], bfr[nt], acc[mt][nt]);
  }
  if (w < 2) {  // q: linear, scaled by 1/8
#pragma unroll
    for (int mt = 0; mt < 4; mt++)
#pragma unroll
      for (int nt = 0; nt < 2; nt++)
#pragma unroll
        for (int j = 0; j < 4; j++)
          q[(size_t)(row0 + mt * 16 + lg * 4 + j) * 64 + nbase + nt * 16 + l15] =
              f2b(acc[mt][nt][j] * 0.125f);
  } else {  // k: swizzled tile-packed
#pragma unroll
    for (int mt = 0; mt < 4; mt++)
#pragma unroll
      for (int nt = 0; nt < 2; nt++)
#pragma unroll
        for (int j = 0; j < 4; j++) {
          int row = row0 + mt * 16 + lg * 4 + j;
          int c = (nbase + nt * 16 + l15) * 2;
          size_t off = (size_t)(row >> 6) * 8192 + (row & 63) * 128 + (c ^ ((row & 7) << 4));
          *(u16*)((char*)kk + off) = f2b(acc[mt][nt][j]);
        }
  }
}

// ---------------- v projection, transposed + swizzle-tile-packed ----------------
// layout: per (b, s-tile 64, d-chunk 128): 16KB block, addr = (d&127)*128 + (((s&63)*2) ^ ((d&7)<<4))
__global__ __launch_bounds__(256) void k_gemm_v(const u16* __restrict__ xb,
                                                const u16* __restrict__ wvt,
                                                u16* __restrict__ vT) {
  int b = blockIdx.z;
  int m0 = blockIdx.y * 128;  // d_out
  int n0 = blockIdx.x * 128;  // s
  int tid = threadIdx.x, w = tid >> 6, l = tid & 63, l15 = l & 15, lg = l >> 4;
  int nb = n0 + w * 32;
  const u16* xrow = xb + (size_t)(b * 4096 + nb) * 1024;
  f32x4 acc[8][2];
#pragma unroll
  for (int mt = 0; mt < 8; mt++)
#pragma unroll
    for (int nt = 0; nt < 2; nt++) acc[mt][nt] = (f32x4){0.f, 0.f, 0.f, 0.f};

  for (int k0 = 0; k0 < 1024; k0 += 32) {
    bf16x8 bfr[2], afr[8];
#pragma unroll
    for (int nt = 0; nt < 2; nt++)
      bfr[nt] = *(const bf16x8*)&xrow[(size_t)(nt * 16 + l15) * 1024 + k0 + lg * 8];
#pragma unroll
    for (int mt = 0; mt < 8; mt++)
      afr[mt] = *(const bf16x8*)&wvt[(size_t)(m0 + mt * 16 + l15) * 1024 + k0 + lg * 8];
#pragma unroll
    for (int mt = 0; mt < 8; mt++)
#pragma unroll
      for (int nt = 0; nt < 2; nt++) acc[mt][nt] = MFMA16(afr[mt], bfr[nt], acc[mt][nt]);
  }
#pragma unroll
  for (int mt = 0; mt < 8; mt++)
#pragma unroll
    for (int nt = 0; nt < 2; nt++)
#pragma unroll
      for (int j = 0; j < 4; j++) {
        int d = m0 + mt * 16 + lg * 4 + j;
        int s = nb + nt * 16 + l15;
        size_t off = ((size_t)(b * 64 + (s >> 6)) * 8 + (d >> 7)) * 16384 + (d & 127) * 128 +
                     (((s & 63) * 2) ^ ((d & 7) << 4));
        *(u16*)((char*)vT + off) = f2b(acc[mt][nt][j]);
      }
}

// ---------------- staged-LDS flash attention ----------------
// Block: 8 waves, 256 q-rows x 128 d-cols; wave = 32q x 128d. Two balanced
// q-tile phases (i, 15-i) -> every block = 68 s-tiles. K(8KB)+V^T(16KB) per
// s-tile double-buffered in LDS via global_load_lds; one barrier per tile.
__global__ __launch_bounds__(512, 2) void k_attn(const u16* __restrict__ qw,
                                                 const u16* __restrict__ kws,
                                                 const u16* __restrict__ vts,
                                                 float* __restrict__ out) {
  int pair = blockIdx.x, chunk = blockIdx.y, b = blockIdx.z;
  int tid = threadIdx.x, w = tid >> 6, l = tid & 63, l15 = l & 15, lg = l >> 4;
  int sw = (l15 & 7) << 4;
  size_t tokb = (size_t)b * 4096;
  int d0 = chunk * 128;

  __shared__ __align__(16) char lds[81920];
  // [0,8K)=K0 [8K,16K)=K1 [16K,32K)=V0 [32K,48K)=V1 [48K,80K)=P(4K/wave)
  char* Pb = lds + 49152 + w * 4096;

  const short ob = (short)0x3F80;
  const bf16x8 ones = {ob, ob, ob, ob, ob, ob, ob, ob};

  auto stage = [&](int t, int bufi) {
    const char* kb = (const char*)kws + (size_t)(b * 64 + t) * 8192;
    const char* vb = (const char*)vts + ((size_t)(b * 64 + t) * 8 + chunk) * 16384;
    char* lk = lds + bufi * 8192;
    char* lv = lds + 16384 + bufi * 16384;
#pragma unroll
    for (int i = 0; i < 3; i++) {
      int s = w * 3 + i;  // wave-uniform slice id, 24 x 1KB total
      if (s < 8) GLLDS(kb + s * 1024 + l * 16, lk + s * 1024);
      else       GLLDS(vb + (s - 8) * 1024 + l * 16, lv + (s - 8) * 1024);
    }
  };

  auto run_phase = [&](int Q0) {
    int ntb = (Q0 >> 6) + 4;        // block trip count
    int qbw = Q0 + w * 32;          // wave's first q-row
    int ntw = (qbw + 95) >> 6;      // wave trip count (<= ntb)

    bf16x8 qf[2][2];
#pragma unroll
    for (int qt = 0; qt < 2; qt++)
#pragma unroll
      for (int ks = 0; ks < 2; ks++)
        qf[qt][ks] = *(const bf16x8*)&qw[(tokb + qbw + qt * 16 + l15) * 64 + ks * 32 + lg * 8];

    f32x4 acc[8][2];   // [d-tile][q-subtile], rows=d cols=q
    f32x4 accl[2];     // row-sum l via ones-MFMA
    float mrow[2][4];  // running max (QK layout)
#pragma unroll
    for (int mt = 0; mt < 8; mt++)
#pragma unroll
      for (int qt = 0; qt < 2; qt++) acc[mt][qt] = (f32x4){0.f, 0.f, 0.f, 0.f};
#pragma unroll
    for (int qt = 0; qt < 2; qt++) {
      accl[qt] = (f32x4){0.f, 0.f, 0.f, 0.f};
#pragma unroll
      for (int j = 0; j < 4; j++) mrow[qt][j] = -1e30f;
    }

    stage(0, 0);
    __syncthreads();
    int buf = 0;
    for (int t = 0; t < ntb; t++) {
      if (t + 1 < ntb) stage(t + 1, buf ^ 1);
      if (t < ntw) {
        const char* Kb = lds + buf * 8192;
        const char* Vb = lds + 16384 + buf * 16384;
        int s0 = t * 64;
        // ---- QK^T from LDS K ----
        f32x4 sfr[2][4];
#pragma unroll
        for (int nt = 0; nt < 4; nt++) {
          const char* kr = Kb + (nt * 16 + l15) * 128;
          bf16x8 kf0 = *(const bf16x8*)(kr + ((lg * 16) ^ sw));
          bf16x8 kf1 = *(const bf16x8*)(kr + ((64 + lg * 16) ^ sw));
#pragma unroll
          for (int qt = 0; qt < 2; qt++) {
            f32x4 z = (f32x4){0.f, 0.f, 0.f, 0.f};
            z = MFMA16(qf[qt][0], kf0, z);
            sfr[qt][nt] = MFMA16(qf[qt][1], kf1, z);
          }
        }
        if (t == ntw - 1) {  // causal mask (only the wave's diagonal tile)
#pragma unroll
          for (int qt = 0; qt < 2; qt++)
#pragma unroll
            for (int nt = 0; nt < 4; nt++) {
              int sg = s0 + nt * 16 + l15;
#pragma unroll
              for (int j = 0; j < 4; j++)
                if (sg > qbw + qt * 16 + lg * 4 + j) sfr[qt][nt][j] = -1e30f;
            }
        }
        // ---- wave-local row max ----
        float pmax[2][4];
        int need = 0;
#pragma unroll
        for (int qt = 0; qt < 2; qt++) {
#pragma unroll
          for (int j = 0; j < 4; j++)
            pmax[qt][j] = fmaxf(fmaxf(sfr[qt][0][j], sfr[qt][1][j]),
                                fmaxf(sfr[qt][2][j], sfr[qt][3][j]));
#pragma unroll
          for (int msk = 1; msk <= 8; msk <<= 1)
#pragma unroll
            for (int j = 0; j < 4; j++)
              pmax[qt][j] = fmaxf(pmax[qt][j], __shfl_xor(pmax[qt][j], msk));
#pragma unroll
          for (int j = 0; j < 4; j++) need |= (pmax[qt][j] > mrow[qt][j] + 8.0f);
        }
        if (__any(need)) {  // T13 defer-max
          float scq[2];
#pragma unroll
          for (int qt = 0; qt < 2; qt++) {
            float sc[4];
#pragma unroll
            for (int j = 0; j < 4; j++) {
              float mn = fmaxf(mrow[qt][j], pmax[qt][j]);
              sc[j] = __expf(mrow[qt][j] - mn);
              mrow[qt][j] = mn;
            }
            float s = 1.f;
#pragma unroll
            for (int j = 0; j < 4; j++) {  // row-scale -> col-scale transpose
              float tv = __shfl(sc[j], (l15 >> 2) * 16);
              if ((l15 & 3) == j) s = tv;
            }
            scq[qt] = s;
          }
#pragma unroll
          for (int mt = 0; mt < 8; mt++)
#pragma unroll
            for (int qt = 0; qt < 2; qt++) acc[mt][qt] *= scq[qt];
          accl[0] *= scq[0];
          accl[1] *= scq[1];
        }
        // ---- P = exp(S-m) -> wave-private swizzled LDS ----
#pragma unroll
        for (int qt = 0; qt < 2; qt++)
#pragma unroll
          for (int nt = 0; nt < 4; nt++)
#pragma unroll
            for (int j = 0; j < 4; j++) {
              int R = qt * 16 + lg * 4 + j;
              float p = __expf(sfr[qt][nt][j] - mrow[qt][j]);
              int addr = (R * 128 + (nt * 16 + l15) * 2) ^ ((R & 7) << 4);
              *(u16*)(Pb + addr) = f2b(p);
            }
        asm volatile("" ::: "memory");
        bf16x8 pf[2][2];
#pragma unroll
        for (int qt = 0; qt < 2; qt++)
#pragma unroll
          for (int ks = 0; ks < 2; ks++) {
            int R = qt * 16 + l15;
            int addr = (R * 128 + ks * 64 + lg * 16) ^ ((R & 7) << 4);
            pf[qt][ks] = *(const bf16x8*)(Pb + addr);
          }
        // ---- l += colsum(P) ----
#pragma unroll
        for (int qt = 0; qt < 2; qt++) {
          accl[qt] = MFMA16(ones, pf[qt][0], accl[qt]);
          accl[qt] = MFMA16(ones, pf[qt][1], accl[qt]);
        }
        // ---- O^T += V^T P^T from LDS V ----
#pragma unroll
        for (int mt = 0; mt < 8; mt++) {
          const char* vr = Vb + (mt * 16 + l15) * 128;
          bf16x8 va0 = *(const bf16x8*)(vr + ((lg * 16) ^ sw));
          bf16x8 va1 = *(const bf16x8*)(vr + ((64 + lg * 16) ^ sw));
#pragma unroll
          for (int qt = 0; qt < 2; qt++) {
            acc[mt][qt] = MFMA16(va0, pf[qt][0], acc[mt][qt]);
            acc[mt][qt] = MFMA16(va1, pf[qt][1], acc[mt][qt]);
          }
        }
      }
      __syncthreads();
      buf ^= 1;
    }
    // ---- epilogue: divide by l, store O ----
#pragma unroll
    for (int qt = 0; qt < 2; qt++) {
      float linv = 1.0f / accl[qt][0];
#pragma unroll
      for (int mt = 0; mt < 8; mt++) {
        f32x4 v = acc[mt][qt] * linv;
        size_t o = (tokb + qbw + qt * 16 + l15) * 1024 + d0 + mt * 16 + lg * 4;
        *(f32x4*)&out[o] = v;
      }
    }
  };

  run_phase(pair * 256);          // light q-tile
  run_phase((15 - pair) * 256);   // heavy q-tile (balanced pair: 68 tiles total)
}

// ---------------- launch ----------------
extern "C" void kernel_launch(void* const* d_in, const int* in_sizes, int n_in,
                              void* d_out, int out_size, void* d_ws, size_t ws_size,
                              hipStream_t stream) {
  const float* x  = (const float*)d_in[0];
  const float* Wq = (const float*)d_in[1];
  const float* Wk = (const float*)d_in[2];
  const float* Wv = (const float*)d_in[3];
  float* out = (float*)d_out;
  char* ws = (char*)d_ws;
  u16* xb  = (u16*)(ws);              // 16384x1024 bf16
  u16* qw  = (u16*)(ws + 33554432);   // 16384x64 (linear)
  u16* kw  = (u16*)(ws + 35651584);   // 256 tiles x 8KB (swizzled)
  u16* vT  = (u16*)(ws + 37748736);   // 2048 tiles x 16KB (swizzled)
  u16* wqt = (u16*)(ws + 71303168);   // 64x1024
  u16* wkt = (u16*)(ws + 71434240);   // 64x1024
  u16* wvt = (u16*)(ws + 71565312);   // 1024x1024

  k_cvt<<<16384, 256, 0, stream>>>(x, xb, 4194304);
  k_packT<<<dim3(32, 2), 256, 0, stream>>>(Wq, wqt, 1024, 64);
  k_packT<<<dim3(32, 2), 256, 0, stream>>>(Wk, wkt, 1024, 64);
  k_packT<<<dim3(32, 32), 256, 0, stream>>>(Wv, wvt, 1024, 1024);
  k_gemm_qk<<<256, 256, 0, stream>>>(xb, wqt, wkt, qw, kw);
  k_gemm_v<<<dim3(32, 8, 4), 256, 0, stream>>>(xb, wvt, vT);
  k_attn<<<dim3(8, 8, 4), 512, 0, stream>>>(qw, kw, vT, out);
}

// Round 5
// 298.925 us; speedup vs baseline: 4.9020x; 1.3568x over previous
//
#include <hip/hip_runtime.h>
#include <hip/hip_bf16.h>

typedef __attribute__((ext_vector_type(8))) short bf16x8;
typedef __attribute__((ext_vector_type(4))) float f32x4;
typedef unsigned short u16;

#define MFMA16(a, b, c) __builtin_amdgcn_mfma_f32_16x16x32_bf16((a), (b), (c), 0, 0, 0)
#define GLLDS(gp, lp)                                                                  \
  __builtin_amdgcn_global_load_lds((const __attribute__((address_space(1))) unsigned int*)(gp), \
                                   (__attribute__((address_space(3))) unsigned int*)(lp), 16, 0, 0)

__device__ __forceinline__ u16 f2b(float f) {
  union { float f; unsigned u; } x; x.f = f;
  return (u16)((x.u + 0x7FFFu + ((x.u >> 16) & 1u)) >> 16);  // RNE
}
__device__ __forceinline__ u16 f2b_hw(float f) {  // native v_cvt path (RNE in hip_bf16.h)
  union { __hip_bfloat16 h; u16 u; } c;
  c.h = __float2bfloat16(f);
  return c.u;
}

// ---------------- x fp32 -> bf16 ----------------
__global__ __launch_bounds__(256) void k_cvt(const float* __restrict__ in,
                                             u16* __restrict__ out, int n4) {
  int i = blockIdx.x * 256 + threadIdx.x;
  if (i >= n4) return;
  float4 v = ((const float4*)in)[i];
  u16 a = f2b(v.x), b = f2b(v.y), c = f2b(v.z), d = f2b(v.w);
  ((uint2*)out)[i] = make_uint2((unsigned)a | ((unsigned)b << 16),
                                (unsigned)c | ((unsigned)d << 16));
}

// ---------------- transpose+convert: out[C][R] = bf16(in[R][C]) ----------------
__global__ __launch_bounds__(256) void k_packT(const float* __restrict__ in,
                                               u16* __restrict__ out, int R, int C) {
  __shared__ float t[32][33];
  int r0 = blockIdx.x * 32, c0 = blockIdx.y * 32;
  int cx = threadIdx.x & 31, ry = threadIdx.x >> 5;
#pragma unroll
  for (int k = 0; k < 4; k++)
    t[ry + k * 8][cx] = in[(size_t)(r0 + ry + k * 8) * C + c0 + cx];
  __syncthreads();
#pragma unroll
  for (int k = 0; k < 4; k++)
    out[(size_t)(c0 + ry + k * 8) * R + r0 + cx] = f2b(t[cx][ry + k * 8]);
}

// ---------------- q,k projection; q linear (pre-scaled 1/8), k swizzle-tile-packed ----------------
__global__ __launch_bounds__(256) void k_gemm_qk(const u16* __restrict__ xb,
                                                 const u16* __restrict__ wqt,
                                                 const u16* __restrict__ wkt,
                                                 u16* __restrict__ q, u16* __restrict__ kk) {
  int row0 = blockIdx.x * 64;
  int tid = threadIdx.x, w = tid >> 6, l = tid & 63, l15 = l & 15, lg = l >> 4;
  const u16* wt = (w < 2) ? wqt : wkt;
  int nbase = (w & 1) * 32;
  f32x4 acc[4][2];
#pragma unroll
  for (int mt = 0; mt < 4; mt++)
#pragma unroll
    for (int nt = 0; nt < 2; nt++) acc[mt][nt] = (f32x4){0.f, 0.f, 0.f, 0.f};

  for (int k0 = 0; k0 < 1024; k0 += 32) {
    bf16x8 bfr[2], afr[4];
#pragma unroll
    for (int nt = 0; nt < 2; nt++)
      bfr[nt] = *(const bf16x8*)&wt[(size_t)(nbase + nt * 16 + l15) * 1024 + k0 + lg * 8];
#pragma unroll
    for (int mt = 0; mt < 4; mt++)
      afr[mt] = *(const bf16x8*)&xb[(size_t)(row0 + mt * 16 + l15) * 1024 + k0 + lg * 8];
#pragma unroll
    for (int mt = 0; mt < 4; mt++)
#pragma unroll
      for (int nt = 0; nt < 2; nt++) acc[mt][nt] = MFMA16(afr[mt], bfr[nt], acc[mt][nt]);
  }
  if (w < 2) {  // q: linear, scaled by 1/8
#pragma unroll
    for (int mt = 0; mt < 4; mt++)
#pragma unroll
      for (int nt = 0; nt < 2; nt++)
#pragma unroll
        for (int j = 0; j < 4; j++)
          q[(size_t)(row0 + mt * 16 + lg * 4 + j) * 64 + nbase + nt * 16 + l15] =
              f2b(acc[mt][nt][j] * 0.125f);
  } else {  // k: swizzled tile-packed
#pragma unroll
    for (int mt = 0; mt < 4; mt++)
#pragma unroll
      for (int nt = 0; nt < 2; nt++)
#pragma unroll
        for (int j = 0; j < 4; j++) {
          int row = row0 + mt * 16 + lg * 4 + j;
          int c = (nbase + nt * 16 + l15) * 2;
          size_t off = (size_t)(row >> 6) * 8192 + (row & 63) * 128 + (c ^ ((row & 7) << 4));
          *(u16*)((char*)kk + off) = f2b(acc[mt][nt][j]);
        }
  }
}

// ---------------- v projection, m97-style staged GEMM, transposed + swizzle-packed out ----------------
// C[d][s] per b: A = wvt[d][k], B = xb[s][k] (both k-contiguous). 128x128 tile, BK=32,
// 4 waves (2x2 of 64x64), double-buffered LDS via global_load_lds.
__global__ __launch_bounds__(256) void k_gemm_v(const u16* __restrict__ xb,
                                                const u16* __restrict__ wvt,
                                                u16* __restrict__ vT) {
  int b = blockIdx.z;
  int d0 = blockIdx.y * 128;
  int s0 = blockIdx.x * 128;
  int tid = threadIdx.x, w = tid >> 6, l = tid & 63, l15 = l & 15, lg = l >> 4;
  int wd = (w & 1) * 64, wsn = (w >> 1) * 64;
  __shared__ __align__(16) char lds[32768];  // [2 buf][A 8K | B 8K], rows of 64B

  const u16* arow = wvt + (size_t)d0 * 1024;
  const u16* brow = xb + (size_t)(b * 4096 + s0) * 1024;

  auto stage = [&](int buf, int k0) {
    char* La = lds + buf * 16384;
    char* Lb = La + 8192;
#pragma unroll
    for (int i = 0; i < 2; i++) {
      int row = w * 32 + i * 16 + (l >> 2), kq = (l & 3) * 8;
      GLLDS(&arow[(size_t)row * 1024 + k0 + kq], La + (w * 2 + i) * 1024);
      GLLDS(&brow[(size_t)row * 1024 + k0 + kq], Lb + (w * 2 + i) * 1024);
    }
  };

  f32x4 acc[4][4];
#pragma unroll
  for (int mt = 0; mt < 4; mt++)
#pragma unroll
    for (int nt = 0; nt < 4; nt++) acc[mt][nt] = (f32x4){0.f, 0.f, 0.f, 0.f};

  stage(0, 0);
  __syncthreads();
  int buf = 0;
  for (int k = 0; k < 32; k++) {
    if (k < 31) stage(buf ^ 1, (k + 1) * 32);
    const char* La = lds + buf * 16384;
    const char* Lb = La + 8192;
    bf16x8 afr[4], bfr[4];
#pragma unroll
    for (int mt = 0; mt < 4; mt++)
      afr[mt] = *(const bf16x8*)(La + (wd + mt * 16 + l15) * 64 + lg * 16);
#pragma unroll
    for (int nt = 0; nt < 4; nt++)
      bfr[nt] = *(const bf16x8*)(Lb + (wsn + nt * 16 + l15) * 64 + lg * 16);
    __builtin_amdgcn_s_setprio(1);
#pragma unroll
    for (int mt = 0; mt < 4; mt++)
#pragma unroll
      for (int nt = 0; nt < 4; nt++) acc[mt][nt] = MFMA16(afr[mt], bfr[nt], acc[mt][nt]);
    __builtin_amdgcn_s_setprio(0);
    __syncthreads();
    buf ^= 1;
  }
#pragma unroll
  for (int mt = 0; mt < 4; mt++)
#pragma unroll
    for (int nt = 0; nt < 4; nt++)
#pragma unroll
      for (int j = 0; j < 4; j++) {
        int d = d0 + wd + mt * 16 + lg * 4 + j;
        int s = s0 + wsn + nt * 16 + l15;
        size_t off = ((size_t)(b * 64 + (s >> 6)) * 8 + (d >> 7)) * 16384 + (d & 127) * 128 +
                     (((s & 63) * 2) ^ ((d & 7) << 4));
        *(u16*)((char*)vT + off) = f2b(acc[mt][nt][j]);
      }
}

// ---------------- staged-LDS flash attention ----------------
__global__ __launch_bounds__(512, 2) void k_attn(const u16* __restrict__ qw,
                                                 const u16* __restrict__ kws,
                                                 const u16* __restrict__ vts,
                                                 float* __restrict__ out) {
  int pair = blockIdx.x, chunk = blockIdx.y, b = blockIdx.z;
  int tid = threadIdx.x, w = tid >> 6, l = tid & 63, l15 = l & 15, lg = l >> 4;
  int sw = (l15 & 7) << 4;
  size_t tokb = (size_t)b * 4096;
  int d0 = chunk * 128;

  __shared__ __align__(16) char lds[81920];
  // [0,8K)=K0 [8K,16K)=K1 [16K,32K)=V0 [32K,48K)=V1 [48K,80K)=P(4K/wave)
  char* Pb = lds + 49152 + w * 4096;

  const short ob = (short)0x3F80;
  const bf16x8 ones = {ob, ob, ob, ob, ob, ob, ob, ob};

  auto stage = [&](int t, int bufi) {
    const char* kb = (const char*)kws + (size_t)(b * 64 + t) * 8192;
    const char* vb = (const char*)vts + ((size_t)(b * 64 + t) * 8 + chunk) * 16384;
    char* lk = lds + bufi * 8192;
    char* lv = lds + 16384 + bufi * 16384;
#pragma unroll
    for (int i = 0; i < 3; i++) {
      int s = w * 3 + i;  // wave-uniform slice id, 24 x 1KB total
      if (s < 8) GLLDS(kb + s * 1024 + l * 16, lk + s * 1024);
      else       GLLDS(vb + (s - 8) * 1024 + l * 16, lv + (s - 8) * 1024);
    }
  };

  auto run_phase = [&](int Q0) {
    int ntb = (Q0 >> 6) + 4;        // block trip count
    int qbw = Q0 + w * 32;          // wave's first q-row
    int ntw = (qbw + 95) >> 6;      // wave trip count (<= ntb)

    bf16x8 qf[2][2];
#pragma unroll
    for (int qt = 0; qt < 2; qt++)
#pragma unroll
      for (int ks = 0; ks < 2; ks++)
        qf[qt][ks] = *(const bf16x8*)&qw[(tokb + qbw + qt * 16 + l15) * 64 + ks * 32 + lg * 8];

    f32x4 acc[8][2];   // [d-tile][q-subtile], rows=d cols=q
    f32x4 accl[2];     // row-sum l via ones-MFMA
    float mrow[2][4];  // running max (QK layout)
#pragma unroll
    for (int mt = 0; mt < 8; mt++)
#pragma unroll
      for (int qt = 0; qt < 2; qt++) acc[mt][qt] = (f32x4){0.f, 0.f, 0.f, 0.f};
#pragma unroll
    for (int qt = 0; qt < 2; qt++) {
      accl[qt] = (f32x4){0.f, 0.f, 0.f, 0.f};
#pragma unroll
      for (int j = 0; j < 4; j++) mrow[qt][j] = -1e30f;
    }

    stage(0, 0);
    __syncthreads();
    int buf = 0;
    for (int t = 0; t < ntb; t++) {
      if (t + 1 < ntb) stage(t + 1, buf ^ 1);
      if (t < ntw) {
        const char* Kb = lds + buf * 8192;
        const char* Vb = lds + 16384 + buf * 16384;
        int s0 = t * 64;
        // ---- QK^T from LDS K ----
        f32x4 sfr[2][4];
        __builtin_amdgcn_s_setprio(1);
#pragma unroll
        for (int nt = 0; nt < 4; nt++) {
          const char* kr = Kb + (nt * 16 + l15) * 128;
          bf16x8 kf0 = *(const bf16x8*)(kr + ((lg * 16) ^ sw));
          bf16x8 kf1 = *(const bf16x8*)(kr + ((64 + lg * 16) ^ sw));
#pragma unroll
          for (int qt = 0; qt < 2; qt++) {
            f32x4 z = (f32x4){0.f, 0.f, 0.f, 0.f};
            z = MFMA16(qf[qt][0], kf0, z);
            sfr[qt][nt] = MFMA16(qf[qt][1], kf1, z);
          }
        }
        __builtin_amdgcn_s_setprio(0);
        if (t == ntw - 1) {  // causal mask (only the wave's diagonal tile)
#pragma unroll
          for (int qt = 0; qt < 2; qt++)
#pragma unroll
            for (int nt = 0; nt < 4; nt++) {
              int sg = s0 + nt * 16 + l15;
#pragma unroll
              for (int j = 0; j < 4; j++)
                if (sg > qbw + qt * 16 + lg * 4 + j) sfr[qt][nt][j] = -1e30f;
            }
        }
        // ---- wave-local row max ----
        float pmax[2][4];
        int need = 0;
#pragma unroll
        for (int qt = 0; qt < 2; qt++) {
#pragma unroll
          for (int j = 0; j < 4; j++)
            pmax[qt][j] = fmaxf(fmaxf(sfr[qt][0][j], sfr[qt][1][j]),
                                fmaxf(sfr[qt][2][j], sfr[qt][3][j]));
#pragma unroll
          for (int msk = 1; msk <= 8; msk <<= 1)
#pragma unroll
            for (int j = 0; j < 4; j++)
              pmax[qt][j] = fmaxf(pmax[qt][j], __shfl_xor(pmax[qt][j], msk));
#pragma unroll
          for (int j = 0; j < 4; j++) need |= (pmax[qt][j] > mrow[qt][j] + 8.0f);
        }
        if (__any(need)) {  // T13 defer-max
          float scq[2];
#pragma unroll
          for (int qt = 0; qt < 2; qt++) {
            float sc[4];
#pragma unroll
            for (int j = 0; j < 4; j++) {
              float mn = fmaxf(mrow[qt][j], pmax[qt][j]);
              sc[j] = __expf(mrow[qt][j] - mn);
              mrow[qt][j] = mn;
            }
            float s = 1.f;
#pragma unroll
            for (int j = 0; j < 4; j++) {  // row-scale -> col-scale transpose
              float tv = __shfl(sc[j], (l15 >> 2) * 16);
              if ((l15 & 3) == j) s = tv;
            }
            scq[qt] = s;
          }
#pragma unroll
          for (int mt = 0; mt < 8; mt++)
#pragma unroll
            for (int qt = 0; qt < 2; qt++) acc[mt][qt] *= scq[qt];
          accl[0] *= scq[0];
          accl[1] *= scq[1];
        }
        // ---- P = exp(S-m) -> wave-private swizzled LDS (native cvt) ----
#pragma unroll
        for (int qt = 0; qt < 2; qt++)
#pragma unroll
          for (int nt = 0; nt < 4; nt++)
#pragma unroll
            for (int j = 0; j < 4; j++) {
              int R = qt * 16 + lg * 4 + j;
              float p = __expf(sfr[qt][nt][j] - mrow[qt][j]);
              int addr = (R * 128 + (nt * 16 + l15) * 2) ^ ((R & 7) << 4);
              *(u16*)(Pb + addr) = f2b_hw(p);
            }
        asm volatile("" ::: "memory");
        bf16x8 pf[2][2];
#pragma unroll
        for (int qt = 0; qt < 2; qt++)
#pragma unroll
          for (int ks = 0; ks < 2; ks++) {
            int R = qt * 16 + l15;
            int addr = (R * 128 + ks * 64 + lg * 16) ^ ((R & 7) << 4);
            pf[qt][ks] = *(const bf16x8*)(Pb + addr);
          }
        // ---- l += colsum(P); O^T += V^T P^T ----
        __builtin_amdgcn_s_setprio(1);
#pragma unroll
        for (int qt = 0; qt < 2; qt++) {
          accl[qt] = MFMA16(ones, pf[qt][0], accl[qt]);
          accl[qt] = MFMA16(ones, pf[qt][1], accl[qt]);
        }
#pragma unroll
        for (int mt = 0; mt < 8; mt++) {
          const char* vr = Vb + (mt * 16 + l15) * 128;
          bf16x8 va0 = *(const bf16x8*)(vr + ((lg * 16) ^ sw));
          bf16x8 va1 = *(const bf16x8*)(vr + ((64 + lg * 16) ^ sw));
#pragma unroll
          for (int qt = 0; qt < 2; qt++) {
            acc[mt][qt] = MFMA16(va0, pf[qt][0], acc[mt][qt]);
            acc[mt][qt] = MFMA16(va1, pf[qt][1], acc[mt][qt]);
          }
        }
        __builtin_amdgcn_s_setprio(0);
      }
      __syncthreads();
      buf ^= 1;
    }
    // ---- epilogue: divide by l, store O ----
#pragma unroll
    for (int qt = 0; qt < 2; qt++) {
      float linv = 1.0f / accl[qt][0];
#pragma unroll
      for (int mt = 0; mt < 8; mt++) {
        f32x4 v = acc[mt][qt] * linv;
        size_t o = (tokb + qbw + qt * 16 + l15) * 1024 + d0 + mt * 16 + lg * 4;
        *(f32x4*)&out[o] = v;
      }
    }
  };

  run_phase(pair * 256);          // light q-tile
  run_phase((15 - pair) * 256);   // heavy q-tile (balanced pair: 68 tiles total)
}

// ---------------- launch ----------------
extern "C" void kernel_launch(void* const* d_in, const int* in_sizes, int n_in,
                              void* d_out, int out_size, void* d_ws, size_t ws_size,
                              hipStream_t stream) {
  const float* x  = (const float*)d_in[0];
  const float* Wq = (const float*)d_in[1];
  const float* Wk = (const float*)d_in[2];
  const float* Wv = (const float*)d_in[3];
  float* out = (float*)d_out;
  char* ws = (char*)d_ws;
  u16* xb  = (u16*)(ws);              // 16384x1024 bf16
  u16* qw  = (u16*)(ws + 33554432);   // 16384x64 (linear)
  u16* kw  = (u16*)(ws + 35651584);   // 256 tiles x 8KB (swizzled)
  u16* vT  = (u16*)(ws + 37748736);   // 2048 tiles x 16KB (swizzled)
  u16* wqt = (u16*)(ws + 71303168);   // 64x1024
  u16* wkt = (u16*)(ws + 71434240);   // 64x1024
  u16* wvt = (u16*)(ws + 71565312);   // 1024x1024

  k_cvt<<<16384, 256, 0, stream>>>(x, xb, 4194304);
  k_packT<<<dim3(32, 2), 256, 0, stream>>>(Wq, wqt, 1024, 64);
  k_packT<<<dim3(32, 2), 256, 0, stream>>>(Wk, wkt, 1024, 64);
  k_packT<<<dim3(32, 32), 256, 0, stream>>>(Wv, wvt, 1024, 1024);
  k_gemm_qk<<<256, 256, 0, stream>>>(xb, wqt, wkt, qw, kw);
  k_gemm_v<<<dim3(32, 8, 4), 256, 0, stream>>>(xb, wvt, vT);
  k_attn<<<dim3(8, 8, 4), 512, 0, stream>>>(qw, kw, vT, out);
}

// Round 6
// 237.494 us; speedup vs baseline: 6.1700x; 1.2587x over previous
//
#include <hip/hip_runtime.h>
#include <hip/hip_bf16.h>

typedef __attribute__((ext_vector_type(8))) short bf16x8;
typedef __attribute__((ext_vector_type(4))) float f32x4;
typedef unsigned short u16;

#define MFMA16(a, b, c) __builtin_amdgcn_mfma_f32_16x16x32_bf16((a), (b), (c), 0, 0, 0)
#define GLLDS(gp, lp)                                                                  \
  __builtin_amdgcn_global_load_lds((const __attribute__((address_space(1))) unsigned int*)(gp), \
                                   (__attribute__((address_space(3))) unsigned int*)(lp), 16, 0, 0)

__device__ __forceinline__ u16 f2b(float f) {
  union { float f; unsigned u; } x; x.f = f;
  return (u16)((x.u + 0x7FFFu + ((x.u >> 16) & 1u)) >> 16);  // RNE
}
__device__ __forceinline__ u16 f2b_hw(float f) {
  union { __hip_bfloat16 h; u16 u; } c;
  c.h = __float2bfloat16(f);
  return c.u;
}

// ---------------- x fp32 -> bf16 ----------------
__global__ __launch_bounds__(256) void k_cvt(const float* __restrict__ in,
                                             u16* __restrict__ out, int n4) {
  int i = blockIdx.x * 256 + threadIdx.x;
  if (i >= n4) return;
  float4 v = ((const float4*)in)[i];
  u16 a = f2b(v.x), b = f2b(v.y), c = f2b(v.z), d = f2b(v.w);
  ((uint2*)out)[i] = make_uint2((unsigned)a | ((unsigned)b << 16),
                                (unsigned)c | ((unsigned)d << 16));
}

// ---------------- transpose+convert: out[C][R] = bf16(in[R][C]) ----------------
__global__ __launch_bounds__(256) void k_packT(const float* __restrict__ in,
                                               u16* __restrict__ out, int R, int C) {
  __shared__ float t[32][33];
  int r0 = blockIdx.x * 32, c0 = blockIdx.y * 32;
  int cx = threadIdx.x & 31, ry = threadIdx.x >> 5;
#pragma unroll
  for (int k = 0; k < 4; k++)
    t[ry + k * 8][cx] = in[(size_t)(r0 + ry + k * 8) * C + c0 + cx];
  __syncthreads();
#pragma unroll
  for (int k = 0; k < 4; k++)
    out[(size_t)(c0 + ry + k * 8) * R + r0 + cx] = f2b(t[cx][ry + k * 8]);
}

// ---------------- q,k projection; q linear (pre-scaled 1/8), k swizzle-tile-packed ----------------
__global__ __launch_bounds__(256) void k_gemm_qk(const u16* __restrict__ xb,
                                                 const u16* __restrict__ wqt,
                                                 const u16* __restrict__ wkt,
                                                 u16* __restrict__ q, u16* __restrict__ kk) {
  int row0 = blockIdx.x * 64;
  int tid = threadIdx.x, w = tid >> 6, l = tid & 63, l15 = l & 15, lg = l >> 4;
  const u16* wt = (w < 2) ? wqt : wkt;
  int nbase = (w & 1) * 32;
  f32x4 acc[4][2];
#pragma unroll
  for (int mt = 0; mt < 4; mt++)
#pragma unroll
    for (int nt = 0; nt < 2; nt++) acc[mt][nt] = (f32x4){0.f, 0.f, 0.f, 0.f};

  for (int k0 = 0; k0 < 1024; k0 += 32) {
    bf16x8 bfr[2], afr[4];
#pragma unroll
    for (int nt = 0; nt < 2; nt++)
      bfr[nt] = *(const bf16x8*)&wt[(size_t)(nbase + nt * 16 + l15) * 1024 + k0 + lg * 8];
#pragma unroll
    for (int mt = 0; mt < 4; mt++)
      afr[mt] = *(const bf16x8*)&xb[(size_t)(row0 + mt * 16 + l15) * 1024 + k0 + lg * 8];
#pragma unroll
    for (int mt = 0; mt < 4; mt++)
#pragma unroll
      for (int nt = 0; nt < 2; nt++) acc[mt][nt] = MFMA16(afr[mt], bfr[nt], acc[mt][nt]);
  }
  if (w < 2) {  // q: linear, scaled by 1/8
#pragma unroll
    for (int mt = 0; mt < 4; mt++)
#pragma unroll
      for (int nt = 0; nt < 2; nt++)
#pragma unroll
        for (int j = 0; j < 4; j++)
          q[(size_t)(row0 + mt * 16 + lg * 4 + j) * 64 + nbase + nt * 16 + l15] =
              f2b(acc[mt][nt][j] * 0.125f);
  } else {  // k: swizzled tile-packed
#pragma unroll
    for (int mt = 0; mt < 4; mt++)
#pragma unroll
      for (int nt = 0; nt < 2; nt++)
#pragma unroll
        for (int j = 0; j < 4; j++) {
          int row = row0 + mt * 16 + lg * 4 + j;
          int c = (nbase + nt * 16 + l15) * 2;
          size_t off = (size_t)(row >> 6) * 8192 + (row & 63) * 128 + (c ^ ((row & 7) << 4));
          *(u16*)((char*)kk + off) = f2b(acc[mt][nt][j]);
        }
  }
}

// ---------------- v projection, m97-style staged GEMM, transposed + swizzle-packed out ----------------
__global__ __launch_bounds__(256) void k_gemm_v(const u16* __restrict__ xb,
                                                const u16* __restrict__ wvt,
                                                u16* __restrict__ vT) {
  int b = blockIdx.z;
  int d0 = blockIdx.y * 128;
  int s0 = blockIdx.x * 128;
  int tid = threadIdx.x, w = tid >> 6, l = tid & 63, l15 = l & 15, lg = l >> 4;
  int wd = (w & 1) * 64, wsn = (w >> 1) * 64;
  __shared__ __align__(16) char lds[32768];

  const u16* arow = wvt + (size_t)d0 * 1024;
  const u16* brow = xb + (size_t)(b * 4096 + s0) * 1024;

  auto stage = [&](int buf, int k0) {
    char* La = lds + buf * 16384;
    char* Lb = La + 8192;
#pragma unroll
    for (int i = 0; i < 2; i++) {
      int row = w * 32 + i * 16 + (l >> 2), kq = (l & 3) * 8;
      GLLDS(&arow[(size_t)row * 1024 + k0 + kq], La + (w * 2 + i) * 1024);
      GLLDS(&brow[(size_t)row * 1024 + k0 + kq], Lb + (w * 2 + i) * 1024);
    }
  };

  f32x4 acc[4][4];
#pragma unroll
  for (int mt = 0; mt < 4; mt++)
#pragma unroll
    for (int nt = 0; nt < 4; nt++) acc[mt][nt] = (f32x4){0.f, 0.f, 0.f, 0.f};

  stage(0, 0);
  __syncthreads();
  int buf = 0;
  for (int k = 0; k < 32; k++) {
    if (k < 31) stage(buf ^ 1, (k + 1) * 32);
    const char* La = lds + buf * 16384;
    const char* Lb = La + 8192;
    bf16x8 afr[4], bfr[4];
#pragma unroll
    for (int mt = 0; mt < 4; mt++)
      afr[mt] = *(const bf16x8*)(La + (wd + mt * 16 + l15) * 64 + lg * 16);
#pragma unroll
    for (int nt = 0; nt < 4; nt++)
      bfr[nt] = *(const bf16x8*)(Lb + (wsn + nt * 16 + l15) * 64 + lg * 16);
    __builtin_amdgcn_s_setprio(1);
#pragma unroll
    for (int mt = 0; mt < 4; mt++)
#pragma unroll
      for (int nt = 0; nt < 4; nt++) acc[mt][nt] = MFMA16(afr[mt], bfr[nt], acc[mt][nt]);
    __builtin_amdgcn_s_setprio(0);
    __syncthreads();
    buf ^= 1;
  }
#pragma unroll
  for (int mt = 0; mt < 4; mt++)
#pragma unroll
    for (int nt = 0; nt < 4; nt++)
#pragma unroll
      for (int j = 0; j < 4; j++) {
        int d = d0 + wd + mt * 16 + lg * 4 + j;
        int s = s0 + wsn + nt * 16 + l15;
        size_t off = ((size_t)(b * 64 + (s >> 6)) * 8 + (d >> 7)) * 16384 + (d & 127) * 128 +
                     (((s & 63) * 2) ^ ((d & 7) << 4));
        *(u16*)((char*)vT + off) = f2b(acc[mt][nt][j]);
      }
}

// ---------------- two-phase shared-P flash attention ----------------
// Block: 8 waves, 128 q x 256 d, 1 block/CU. Per 64-key s-tile:
//  Phase A: wave w = 16 q-rows [Q0+w*16, +16): swapped QK (S cols=q per lane),
//           reg-local softmax, P(128x64 bf16, swizzled) + sc -> shared LDS.
//  Phase B: wave = (q-pos w&3: 32 rows) x (d-half w>>2: 128): PV + ones-MFMA.
// Softmax+QK cost halves globally vs d-chunk=8 replication.
__global__ __launch_bounds__(512, 2) void k_attn(const u16* __restrict__ qw,
                                                 const u16* __restrict__ kws,
                                                 const u16* __restrict__ vts,
                                                 float* __restrict__ out) {
  int p = blockIdx.x, cpair = blockIdx.y, b = blockIdx.z;
  int tid = threadIdx.x, w = tid >> 6, l = tid & 63, l15 = l & 15, lg = l >> 4;
  int sw = (l15 & 7) << 4;
  size_t tokb = (size_t)b * 4096;

  __shared__ __align__(16) char lds[98816];
  // [0,16K)=K dbuf  [16K,80K)=V dbuf(32K each)  [80K,96K)=P  [96K,+512)=sc
  char* Pb = lds + 81920;
  float* scb = (float*)(lds + 98304);

  const short ob = (short)0x3F80;
  const bf16x8 ones = {ob, ob, ob, ob, ob, ob, ob, ob};

  auto stage = [&](int t, int bufi) {
    const char* kb = (const char*)kws + (size_t)(b * 64 + t) * 8192;
    const char* vb = (const char*)vts + ((size_t)(b * 64 + t) * 8 + cpair * 2) * 16384;
    char* lk = lds + bufi * 8192;
    char* lv = lds + 16384 + bufi * 32768;
#pragma unroll
    for (int i = 0; i < 5; i++) {
      int s = w * 5 + i;  // 40 x 1KB slices: 8 K + 32 V
      if (s < 8) GLLDS(kb + s * 1024 + l * 16, lk + s * 1024);
      else       GLLDS(vb + (s - 8) * 1024 + l * 16, lv + (s - 8) * 1024);
    }
  };

  auto run_phase = [&](int Q0) {
    int ntb = (Q0 >> 6) + 2;
    int qsA = Q0 + w * 16;        // writer q-range start
    int qA = qsA + l15;           // writer's q (per lane)
    int qsB = Q0 + (w & 3) * 32;  // PV q-range start
    int dhalf = w >> 2;

    bf16x8 qf[2];
#pragma unroll
    for (int ks = 0; ks < 2; ks++)
      qf[ks] = *(const bf16x8*)&qw[(tokb + qA) * 64 + ks * 32 + lg * 8];

    f32x4 acc[8][2], accl[2];
    float mrow = -1e30f;
#pragma unroll
    for (int mt = 0; mt < 8; mt++)
#pragma unroll
      for (int qt = 0; qt < 2; qt++) acc[mt][qt] = (f32x4){0.f, 0.f, 0.f, 0.f};
    accl[0] = (f32x4){0.f, 0.f, 0.f, 0.f};
    accl[1] = (f32x4){0.f, 0.f, 0.f, 0.f};

    stage(0, 0);
    __syncthreads();
    int buf = 0;
    for (int t = 0; t < ntb; t++) {
      int s0 = t * 64;
      if (t + 1 < ntb) stage(t + 1, buf ^ 1);
      // ---- phase A: swapped QK + softmax + P/sc write ----
      if (s0 < qsA + 16) {
        const char* Kb = lds + buf * 8192;
        f32x4 sfr[4];
        __builtin_amdgcn_s_setprio(1);
#pragma unroll
        for (int nt = 0; nt < 4; nt++) {
          const char* kr = Kb + (nt * 16 + l15) * 128;
          bf16x8 kf0 = *(const bf16x8*)(kr + ((lg * 16) ^ sw));
          bf16x8 kf1 = *(const bf16x8*)(kr + ((64 + lg * 16) ^ sw));
          f32x4 z = (f32x4){0.f, 0.f, 0.f, 0.f};
          z = MFMA16(kf0, qf[0], z);  // swapped: rows=s, cols=q
          sfr[nt] = MFMA16(kf1, qf[1], z);
        }
        __builtin_amdgcn_s_setprio(0);
        if (s0 + 63 > qsA) {  // causal mask: s > q
#pragma unroll
          for (int nt = 0; nt < 4; nt++)
#pragma unroll
            for (int j = 0; j < 4; j++)
              if (s0 + nt * 16 + lg * 4 + j > qA) sfr[nt][j] = -1e30f;
        }
        // row-max over s: 16 reg-local + 2 shfl (lane-groups)
        float pm = fmaxf(fmaxf(fmaxf(sfr[0][0], sfr[0][1]), fmaxf(sfr[0][2], sfr[0][3])),
                         fmaxf(fmaxf(sfr[1][0], sfr[1][1]), fmaxf(sfr[1][2], sfr[1][3])));
        pm = fmaxf(pm, fmaxf(fmaxf(fmaxf(sfr[2][0], sfr[2][1]), fmaxf(sfr[2][2], sfr[2][3])),
                             fmaxf(fmaxf(sfr[3][0], sfr[3][1]), fmaxf(sfr[3][2], sfr[3][3]))));
        pm = fmaxf(pm, __shfl_xor(pm, 16));
        pm = fmaxf(pm, __shfl_xor(pm, 32));
        float sc = 1.0f;
        if (__any(pm > mrow + 8.0f)) {  // T13 defer-max
          float mn = fmaxf(mrow, pm);
          sc = __expf(mrow - mn);
          mrow = mn;
        }
        int rq = w * 16 + l15;
        scb[rq] = sc;
        int rbase = rq * 128, sx = (rq & 7) << 4;
#pragma unroll
        for (int nt = 0; nt < 4; nt++) {  // 4 s-consecutive -> one b64 write
          unsigned lo = (unsigned)f2b_hw(__expf(sfr[nt][0] - mrow)) |
                        ((unsigned)f2b_hw(__expf(sfr[nt][1] - mrow)) << 16);
          unsigned hi = (unsigned)f2b_hw(__expf(sfr[nt][2] - mrow)) |
                        ((unsigned)f2b_hw(__expf(sfr[nt][3] - mrow)) << 16);
          int addr = (rbase + (nt * 16 + lg * 4) * 2) ^ sx;
          *(uint2*)(Pb + addr) = make_uint2(lo, hi);
        }
      }
      __syncthreads();  // P + sc ready
      // ---- phase B: PV on 32q x 128d ----
      const char* Vb = lds + 16384 + buf * 32768 + dhalf * 16384;
#pragma unroll
      for (int qt = 0; qt < 2; qt++) {
        if (s0 < qsB + qt * 16 + 16) {
          float sq = scb[(w & 3) * 32 + qt * 16 + l15];
          if (!__all(sq == 1.0f)) {
#pragma unroll
            for (int mt = 0; mt < 8; mt++) acc[mt][qt] *= sq;
            accl[qt] *= sq;
          }
          int R = (w & 3) * 32 + qt * 16 + l15;
          int rx = (R & 7) << 4;
          bf16x8 pf0 = *(const bf16x8*)(Pb + ((R * 128 + lg * 16) ^ rx));
          bf16x8 pf1 = *(const bf16x8*)(Pb + ((R * 128 + 64 + lg * 16) ^ rx));
          __builtin_amdgcn_s_setprio(1);
          accl[qt] = MFMA16(ones, pf0, accl[qt]);
          accl[qt] = MFMA16(ones, pf1, accl[qt]);
#pragma unroll
          for (int mt = 0; mt < 8; mt++) {
            const char* vr = Vb + (mt * 16 + l15) * 128;
            bf16x8 va0 = *(const bf16x8*)(vr + ((lg * 16) ^ sw));
            bf16x8 va1 = *(const bf16x8*)(vr + ((64 + lg * 16) ^ sw));
            acc[mt][qt] = MFMA16(va0, pf0, acc[mt][qt]);
            acc[mt][qt] = MFMA16(va1, pf1, acc[mt][qt]);
          }
          __builtin_amdgcn_s_setprio(0);
        }
      }
      __syncthreads();  // buf free for next stage
      buf ^= 1;
    }
    // ---- epilogue ----
#pragma unroll
    for (int qt = 0; qt < 2; qt++) {
      float linv = 1.0f / accl[qt][0];
#pragma unroll
      for (int mt = 0; mt < 8; mt++) {
        f32x4 v = acc[mt][qt] * linv;
        size_t o = (tokb + qsB + qt * 16 + l15) * 1024 + cpair * 256 + dhalf * 128 +
                   mt * 16 + lg * 4;
        *(f32x4*)&out[o] = v;
      }
    }
  };

  run_phase(p * 128);          // light q-tile
  run_phase((31 - p) * 128);   // heavy q-tile (balanced: 66 tiles/block)
}

// ---------------- launch ----------------
extern "C" void kernel_launch(void* const* d_in, const int* in_sizes, int n_in,
                              void* d_out, int out_size, void* d_ws, size_t ws_size,
                              hipStream_t stream) {
  const float* x  = (const float*)d_in[0];
  const float* Wq = (const float*)d_in[1];
  const float* Wk = (const float*)d_in[2];
  const float* Wv = (const float*)d_in[3];
  float* out = (float*)d_out;
  char* ws = (char*)d_ws;
  u16* xb  = (u16*)(ws);              // 16384x1024 bf16
  u16* qw  = (u16*)(ws + 33554432);   // 16384x64 (linear)
  u16* kw  = (u16*)(ws + 35651584);   // 256 tiles x 8KB (swizzled)
  u16* vT  = (u16*)(ws + 37748736);   // 2048 tiles x 16KB (swizzled)
  u16* wqt = (u16*)(ws + 71303168);   // 64x1024
  u16* wkt = (u16*)(ws + 71434240);   // 64x1024
  u16* wvt = (u16*)(ws + 71565312);   // 1024x1024

  k_cvt<<<16384, 256, 0, stream>>>(x, xb, 4194304);
  k_packT<<<dim3(32, 2), 256, 0, stream>>>(Wq, wqt, 1024, 64);
  k_packT<<<dim3(32, 2), 256, 0, stream>>>(Wk, wkt, 1024, 64);
  k_packT<<<dim3(32, 32), 256, 0, stream>>>(Wv, wvt, 1024, 1024);
  k_gemm_qk<<<256, 256, 0, stream>>>(xb, wqt, wkt, qw, kw);
  k_gemm_v<<<dim3(32, 8, 4), 256, 0, stream>>>(xb, wvt, vT);
  k_attn<<<dim3(16, 4, 4), 512, 0, stream>>>(qw, kw, vT, out);
}